// Round 1
// baseline (1163.283 us; speedup 1.0000x reference)
//
#include <hip/hip_runtime.h>

// N=100000 nodes, E=1250000 edges, all dims 64.
// Strategy: device-built CSR (by dst), then two fused per-node kernels:
//   layer1: gather x (GCN-weighted + SAGE-sum) -> fused GEMMs -> relu -> g, s1
//   layer2: gather g,s1 -> fused GEMMs -> LayerNorm -> concat-proj -> out
// One wave (64 lanes) per node; lane = feature. Weights in LDS; inner
// products via __shfl broadcast; LN via 64-lane butterfly. No float atomics.

#define SCAN_CHUNK 2048  // 256 threads * 8 elements

__global__ void k_count(const int* __restrict__ ei, int E, int* __restrict__ cnt) {
    int e = blockIdx.x * blockDim.x + threadIdx.x;
    if (e < E) atomicAdd(&cnt[ei[E + e]], 1);
}

__global__ void k_scan_reduce(const int* __restrict__ cnt, int N, int* __restrict__ blockSums) {
    __shared__ int lds[256];
    int base = blockIdx.x * SCAN_CHUNK;
    int t = threadIdx.x;
    int s = 0;
    for (int j = 0; j < 8; ++j) {
        int idx = base + t * 8 + j;
        if (idx < N) s += cnt[idx];
    }
    lds[t] = s;
    __syncthreads();
    for (int d = 128; d > 0; d >>= 1) {
        if (t < d) lds[t] += lds[t + d];
        __syncthreads();
    }
    if (t == 0) blockSums[blockIdx.x] = lds[0];
}

__global__ void k_scan_spine(int* __restrict__ blockSums, int B) {
    if (threadIdx.x == 0 && blockIdx.x == 0) {
        int run = 0;
        for (int b = 0; b < B; ++b) { int v = blockSums[b]; blockSums[b] = run; run += v; }
    }
}

__global__ void k_scan_write(const int* __restrict__ cnt, int N,
                             const int* __restrict__ blockSums,
                             int* __restrict__ offs, float* __restrict__ dinv) {
    __shared__ int lds[256];
    int base = blockIdx.x * SCAN_CHUNK;
    int t = threadIdx.x;
    int v[8];
    int s = 0;
    for (int j = 0; j < 8; ++j) {
        int idx = base + t * 8 + j;
        v[j] = (idx < N) ? cnt[idx] : 0;
        s += v[j];
    }
    lds[t] = s;
    __syncthreads();
    // inclusive Hillis-Steele scan over thread sums
    for (int d = 1; d < 256; d <<= 1) {
        int x = (t >= d) ? lds[t - d] : 0;
        __syncthreads();
        lds[t] += x;
        __syncthreads();
    }
    int excl = (t == 0) ? 0 : lds[t - 1];
    int run = blockSums[blockIdx.x] + excl;
    for (int j = 0; j < 8; ++j) {
        int idx = base + t * 8 + j;
        if (idx < N) {
            offs[idx] = run;
            run += v[j];
            dinv[idx] = rsqrtf((float)v[j] + 1.0f);  // deg includes +1 self loop
        }
    }
}

__global__ void k_fill(const int* __restrict__ ei, int E, const int* __restrict__ offs,
                       int* __restrict__ cursor, int* __restrict__ csr) {
    int e = blockIdx.x * blockDim.x + threadIdx.x;
    if (e < E) {
        int s = ei[e];
        int d = ei[E + e];
        int pos = offs[d] + atomicAdd(&cursor[d], 1);
        csr[pos] = s;
    }
}

// Layer 1: per node i
//   aggA = sum_e dinv[src]*dinv[i] * x[src]   (GCN, pre-GEMM thanks to linearity)
//   aggB = sum_e x[src]                        (SAGE)
//   g  = relu((aggA + x_i*dinv_i^2) @ W1 + b1)
//   s1 = relu((aggB/max(cnt,1)) @ Wl1 + bl1 + x_i @ Wr1)
__launch_bounds__(1024)
__global__ void k_layer1(const float* __restrict__ x, const int* __restrict__ csr,
                         const int* __restrict__ offs, const int* __restrict__ cnt,
                         const float* __restrict__ dinv,
                         const float* __restrict__ W1, const float* __restrict__ b1,
                         const float* __restrict__ Wl1, const float* __restrict__ bl1,
                         const float* __restrict__ Wr1,
                         float* __restrict__ g, float* __restrict__ s1, int N) {
    __shared__ float sW1[4096], sWl[4096], sWr[4096];
    __shared__ float sb1[64], sbl[64];
    int t = threadIdx.x;
    for (int i = t; i < 4096; i += 1024) {
        sW1[i] = W1[i];
        sWl[i] = Wl1[i];
        sWr[i] = Wr1[i];
    }
    if (t < 64) { sb1[t] = b1[t]; sbl[t] = bl1[t]; }
    __syncthreads();

    int lane = t & 63;
    int wave = t >> 6;
    int node = blockIdx.x * 16 + wave;
    if (node >= N) return;

    int st = offs[node];
    int cn = cnt[node];
    float di = dinv[node];

    float accA = 0.f, accB = 0.f;
    int e = 0;
    for (; e + 4 <= cn; e += 4) {
        int s0 = csr[st + e], s1i = csr[st + e + 1], s2 = csr[st + e + 2], s3 = csr[st + e + 3];
        float w0 = dinv[s0] * di, w1 = dinv[s1i] * di, w2 = dinv[s2] * di, w3 = dinv[s3] * di;
        float v0 = x[s0 * 64 + lane], v1 = x[s1i * 64 + lane];
        float v2 = x[s2 * 64 + lane], v3 = x[s3 * 64 + lane];
        accA += w0 * v0 + w1 * v1 + w2 * v2 + w3 * v3;
        accB += v0 + v1 + v2 + v3;
    }
    for (; e < cn; ++e) {
        int s = csr[st + e];
        float w = dinv[s] * di;
        float v = x[s * 64 + lane];
        accA += w * v;
        accB += v;
    }

    float xv = x[node * 64 + lane];
    float gin = accA + xv * di * di;
    float sin_ = accB / fmaxf((float)cn, 1.0f);

    float accG = sb1[lane], accS = sbl[lane];
    #pragma unroll 8
    for (int k = 0; k < 64; ++k) {
        float gk = __shfl(gin, k, 64);
        float bk = __shfl(sin_, k, 64);
        float xk = __shfl(xv, k, 64);
        accG += gk * sW1[k * 64 + lane];
        accS += bk * sWl[k * 64 + lane] + xk * sWr[k * 64 + lane];
    }
    g[node * 64 + lane] = fmaxf(accG, 0.f);
    s1[node * 64 + lane] = fmaxf(accS, 0.f);
}

// Layer 2 + LayerNorms + concat-proj, fused per node.
__launch_bounds__(1024)
__global__ void k_layer2(const float* __restrict__ g, const float* __restrict__ s1,
                         const int* __restrict__ csr, const int* __restrict__ offs,
                         const int* __restrict__ cnt, const float* __restrict__ dinv,
                         const float* __restrict__ W2, const float* __restrict__ b2,
                         const float* __restrict__ Wl2, const float* __restrict__ bl2,
                         const float* __restrict__ Wr2,
                         const float* __restrict__ lngG, const float* __restrict__ lnbG,
                         const float* __restrict__ lngS, const float* __restrict__ lnbS,
                         const float* __restrict__ Pw, const float* __restrict__ Pb,
                         float* __restrict__ out, int N) {
    __shared__ float sW2[4096], sWl[4096], sWr[4096], sP[8192];
    __shared__ float sb2[64], sbl[64], sgG[64], sbG[64], sgS[64], sbS[64], sPb[64];
    int t = threadIdx.x;
    for (int i = t; i < 4096; i += 1024) {
        sW2[i] = W2[i];
        sWl[i] = Wl2[i];
        sWr[i] = Wr2[i];
    }
    for (int i = t; i < 8192; i += 1024) sP[i] = Pw[i];
    if (t < 64) {
        sb2[t] = b2[t]; sbl[t] = bl2[t];
        sgG[t] = lngG[t]; sbG[t] = lnbG[t];
        sgS[t] = lngS[t]; sbS[t] = lnbS[t];
        sPb[t] = Pb[t];
    }
    __syncthreads();

    int lane = t & 63;
    int wave = t >> 6;
    int node = blockIdx.x * 16 + wave;
    if (node >= N) return;

    int st = offs[node];
    int cn = cnt[node];
    float di = dinv[node];

    float accC = 0.f, accD = 0.f;
    int e = 0;
    for (; e + 4 <= cn; e += 4) {
        int s0 = csr[st + e], s1i = csr[st + e + 1], s2 = csr[st + e + 2], s3 = csr[st + e + 3];
        float w0 = dinv[s0] * di, w1 = dinv[s1i] * di, w2 = dinv[s2] * di, w3 = dinv[s3] * di;
        float g0 = g[s0 * 64 + lane], g1 = g[s1i * 64 + lane];
        float g2 = g[s2 * 64 + lane], g3 = g[s3 * 64 + lane];
        float t0 = s1[s0 * 64 + lane], t1 = s1[s1i * 64 + lane];
        float t2 = s1[s2 * 64 + lane], t3 = s1[s3 * 64 + lane];
        accC += w0 * g0 + w1 * g1 + w2 * g2 + w3 * g3;
        accD += t0 + t1 + t2 + t3;
    }
    for (; e < cn; ++e) {
        int s = csr[st + e];
        float w = dinv[s] * di;
        accC += w * g[s * 64 + lane];
        accD += s1[s * 64 + lane];
    }

    float gv = g[node * 64 + lane];
    float sv = s1[node * 64 + lane];
    float g2in = accC + gv * di * di;
    float s2in = accD / fmaxf((float)cn, 1.0f);

    float accG2 = sb2[lane], accS2 = sbl[lane];
    #pragma unroll 8
    for (int k = 0; k < 64; ++k) {
        float gk = __shfl(g2in, k, 64);
        float dk = __shfl(s2in, k, 64);
        float sk = __shfl(sv, k, 64);
        accG2 += gk * sW2[k * 64 + lane];
        accS2 += dk * sWl[k * 64 + lane] + sk * sWr[k * 64 + lane];
    }

    // LayerNorm over 64 lanes, both branches (population variance, eps=1e-5)
    float sG = accG2, qG = accG2 * accG2;
    float sS = accS2, qS = accS2 * accS2;
    #pragma unroll
    for (int m = 1; m < 64; m <<= 1) {
        sG += __shfl_xor(sG, m, 64);
        qG += __shfl_xor(qG, m, 64);
        sS += __shfl_xor(sS, m, 64);
        qS += __shfl_xor(qS, m, 64);
    }
    float muG = sG * (1.0f / 64.0f);
    float varG = fmaxf(qG * (1.0f / 64.0f) - muG * muG, 0.0f);
    float muS = sS * (1.0f / 64.0f);
    float varS = fmaxf(qS * (1.0f / 64.0f) - muS * muS, 0.0f);
    float gln = (accG2 - muG) * rsqrtf(varG + 1e-5f) * sgG[lane] + sbG[lane];
    float sln = (accS2 - muS) * rsqrtf(varS + 1e-5f) * sgS[lane] + sbS[lane];

    // concat([gln, sln]) @ Pw + Pb
    float accO = sPb[lane];
    #pragma unroll 8
    for (int k = 0; k < 64; ++k) {
        float a = __shfl(gln, k, 64);
        accO += a * sP[k * 64 + lane];
    }
    #pragma unroll 8
    for (int k = 0; k < 64; ++k) {
        float a = __shfl(sln, k, 64);
        accO += a * sP[(64 + k) * 64 + lane];
    }
    out[node * 64 + lane] = accO;
}

extern "C" void kernel_launch(void* const* d_in, const int* in_sizes, int n_in,
                              void* d_out, int out_size, void* d_ws, size_t ws_size,
                              hipStream_t stream) {
    const float* x       = (const float*)d_in[0];
    const int*   ei      = (const int*)d_in[1];
    const float* gcn_w1  = (const float*)d_in[2];
    const float* gcn_b1  = (const float*)d_in[3];
    const float* gcn_w2  = (const float*)d_in[4];
    const float* gcn_b2  = (const float*)d_in[5];
    const float* sage_wl1 = (const float*)d_in[6];
    const float* sage_bl1 = (const float*)d_in[7];
    const float* sage_wr1 = (const float*)d_in[8];
    const float* sage_wl2 = (const float*)d_in[9];
    const float* sage_bl2 = (const float*)d_in[10];
    const float* sage_wr2 = (const float*)d_in[11];
    const float* gcn_ln_g = (const float*)d_in[12];
    const float* gcn_ln_b = (const float*)d_in[13];
    const float* sage_ln_g = (const float*)d_in[14];
    const float* sage_ln_b = (const float*)d_in[15];
    const float* proj_w   = (const float*)d_in[16];
    const float* proj_b   = (const float*)d_in[17];
    float* out = (float*)d_out;

    const int N = in_sizes[0] / 64;
    const int E = in_sizes[1] / 2;
    const int B = (N + SCAN_CHUNK - 1) / SCAN_CHUNK;

    // workspace carve-up (256B-aligned regions)
    char* w = (char*)d_ws;
    size_t off = 0;
    auto alloc = [&](size_t bytes) -> void* {
        void* p = w + off;
        off = (off + bytes + 255) & ~(size_t)255;
        return p;
    };
    int*   cnt      = (int*)alloc((size_t)N * 4);
    int*   offs     = (int*)alloc((size_t)N * 4);
    int*   cursor   = (int*)alloc((size_t)N * 4);
    float* dinv     = (float*)alloc((size_t)N * 4);
    int*   blockSums = (int*)alloc((size_t)(B + 1) * 4);
    int*   csr      = (int*)alloc((size_t)E * 4);
    float* g        = (float*)alloc((size_t)N * 64 * 4);
    float* s1       = (float*)alloc((size_t)N * 64 * 4);
    (void)ws_size; (void)n_in; (void)out_size;

    hipMemsetAsync(cnt, 0, (size_t)N * 4, stream);
    hipMemsetAsync(cursor, 0, (size_t)N * 4, stream);

    int eBlocks = (E + 255) / 256;
    k_count<<<eBlocks, 256, 0, stream>>>(ei, E, cnt);
    k_scan_reduce<<<B, 256, 0, stream>>>(cnt, N, blockSums);
    k_scan_spine<<<1, 64, 0, stream>>>(blockSums, B);
    k_scan_write<<<B, 256, 0, stream>>>(cnt, N, blockSums, offs, dinv);
    k_fill<<<eBlocks, 256, 0, stream>>>(ei, E, offs, cursor, csr);

    int nodeBlocks = (N + 15) / 16;
    k_layer1<<<nodeBlocks, 1024, 0, stream>>>(x, csr, offs, cnt, dinv,
                                              gcn_w1, gcn_b1, sage_wl1, sage_bl1, sage_wr1,
                                              g, s1, N);
    k_layer2<<<nodeBlocks, 1024, 0, stream>>>(g, s1, csr, offs, cnt, dinv,
                                              gcn_w2, gcn_b2, sage_wl2, sage_bl2, sage_wr2,
                                              gcn_ln_g, gcn_ln_b, sage_ln_g, sage_ln_b,
                                              proj_w, proj_b, out, N);
}

// Round 2
// 946.045 us; speedup vs baseline: 1.2296x; 1.2296x over previous
//
#include <hip/hip_runtime.h>

// N=100000 nodes, E=1250000 edges, all dims 64. fp32 end-to-end.
// R2 restructure: LDS-pipe was the bottleneck (664 DS-ops/node @5.8cyc in the
// shuffle-GEMM ≈ measured 648us). New datapath:
//  - weights transposed in LDS (stride 68), read as ds_read_b128 (1KB/op)
//  - input broadcasts via wave-uniform b128 reads / scalar-cache global loads
//    (readfirstlane-forced) instead of __shfl (ds_bpermute)
//  - layer1 split: k_gather1 (float4-lane, 4 edges/wave-iter, no LDS, high MLP)
//    then k_gemm1 (2 nodes/wave, weight reads amortized), in-place agg->gs
//  - layer2 stays fused (gather+GEMM+LN+proj) to avoid extra 51MB workspace

#define SCAN_CHUNK 2048

__global__ void k_count(const int* __restrict__ ei, int E, int* __restrict__ cnt) {
    int i = blockIdx.x * blockDim.x + threadIdx.x;
    int e = i * 4;
    if (e + 4 <= E) {
        int4 d = *(const int4*)&ei[E + e];
        atomicAdd(&cnt[d.x], 1); atomicAdd(&cnt[d.y], 1);
        atomicAdd(&cnt[d.z], 1); atomicAdd(&cnt[d.w], 1);
    } else {
        for (int j = e; j < E; ++j) atomicAdd(&cnt[ei[E + j]], 1);
    }
}

__global__ void k_scan_reduce(const int* __restrict__ cnt, int N, int* __restrict__ blockSums) {
    __shared__ int lds[256];
    int base = blockIdx.x * SCAN_CHUNK;
    int t = threadIdx.x;
    int s = 0;
    for (int j = 0; j < 8; ++j) {
        int idx = base + t * 8 + j;
        if (idx < N) s += cnt[idx];
    }
    lds[t] = s;
    __syncthreads();
    for (int d = 128; d > 0; d >>= 1) {
        if (t < d) lds[t] += lds[t + d];
        __syncthreads();
    }
    if (t == 0) blockSums[blockIdx.x] = lds[0];
}

__global__ void k_scan_spine(int* __restrict__ blockSums, int B) {
    if (threadIdx.x == 0 && blockIdx.x == 0) {
        int run = 0;
        for (int b = 0; b < B; ++b) { int v = blockSums[b]; blockSums[b] = run; run += v; }
    }
}

__global__ void k_scan_write(const int* __restrict__ cnt, int N,
                             const int* __restrict__ blockSums,
                             int* __restrict__ offs, float* __restrict__ dinv) {
    __shared__ int lds[256];
    int base = blockIdx.x * SCAN_CHUNK;
    int t = threadIdx.x;
    int v[8];
    int s = 0;
    for (int j = 0; j < 8; ++j) {
        int idx = base + t * 8 + j;
        v[j] = (idx < N) ? cnt[idx] : 0;
        s += v[j];
    }
    lds[t] = s;
    __syncthreads();
    for (int d = 1; d < 256; d <<= 1) {
        int x = (t >= d) ? lds[t - d] : 0;
        __syncthreads();
        lds[t] += x;
        __syncthreads();
    }
    int excl = (t == 0) ? 0 : lds[t - 1];
    int run = blockSums[blockIdx.x] + excl;
    for (int j = 0; j < 8; ++j) {
        int idx = base + t * 8 + j;
        if (idx < N) {
            offs[idx] = run;
            run += v[j];
            dinv[idx] = rsqrtf((float)v[j] + 1.0f);
        }
    }
}

__global__ void k_fill(const int* __restrict__ ei, int E, const int* __restrict__ offs,
                       int* __restrict__ cursor, int* __restrict__ csr) {
    int i = blockIdx.x * blockDim.x + threadIdx.x;
    int e = i * 4;
    if (e + 4 <= E) {
        int4 s = *(const int4*)&ei[e];
        int4 d = *(const int4*)&ei[E + e];
        csr[offs[d.x] + atomicAdd(&cursor[d.x], 1)] = s.x;
        csr[offs[d.y] + atomicAdd(&cursor[d.y], 1)] = s.y;
        csr[offs[d.z] + atomicAdd(&cursor[d.z], 1)] = s.z;
        csr[offs[d.w] + atomicAdd(&cursor[d.w], 1)] = s.w;
    } else {
        for (int j = e; j < E; ++j) {
            int s = ei[j], d = ei[E + j];
            csr[offs[d] + atomicAdd(&cursor[d], 1)] = s;
        }
    }
}

__device__ __forceinline__ void xor_reduce8(float4& a, float4& b) {
    a.x += __shfl_xor(a.x, 16, 64); a.y += __shfl_xor(a.y, 16, 64);
    a.z += __shfl_xor(a.z, 16, 64); a.w += __shfl_xor(a.w, 16, 64);
    b.x += __shfl_xor(b.x, 16, 64); b.y += __shfl_xor(b.y, 16, 64);
    b.z += __shfl_xor(b.z, 16, 64); b.w += __shfl_xor(b.w, 16, 64);
    a.x += __shfl_xor(a.x, 32, 64); a.y += __shfl_xor(a.y, 32, 64);
    a.z += __shfl_xor(a.z, 32, 64); a.w += __shfl_xor(a.w, 32, 64);
    b.x += __shfl_xor(b.x, 32, 64); b.y += __shfl_xor(b.y, 32, 64);
    b.z += __shfl_xor(b.z, 32, 64); b.w += __shfl_xor(b.w, 32, 64);
}

// Gather layer-1 inputs: one wave per node; lane = (edge_group grp=lane>>4,
// feature-quad c=lane&15). Writes buf1[node][0:64]=gin (GCN input incl self),
// buf1[node][64:128]=sin (SAGE mean). No LDS -> full occupancy, high MLP.
__global__ void k_gather1(const float* __restrict__ x, const int* __restrict__ csr,
                          const int* __restrict__ offs, const int* __restrict__ cnt,
                          const float* __restrict__ dinv,
                          float* __restrict__ buf1, int N) {
    int lane = threadIdx.x & 63;
    int wave = threadIdx.x >> 6;
    int node = blockIdx.x * 4 + wave;
    if (node >= N) return;
    int c = lane & 15, grp = lane >> 4;

    int st = offs[node];
    int cn = cnt[node];
    float di = dinv[node];

    float4 aA = {0.f, 0.f, 0.f, 0.f}, aB = {0.f, 0.f, 0.f, 0.f};
    for (int e = 0; e < cn; e += 8) {
        int i0 = e + grp, i1 = e + 4 + grp;
        float m0 = (i0 < cn) ? 1.f : 0.f;
        float m1 = (i1 < cn) ? 1.f : 0.f;
        int s0 = csr[st + (i0 < cn ? i0 : cn - 1)];
        int s1 = csr[st + (i1 < cn ? i1 : cn - 1)];
        float w0 = m0 * dinv[s0];
        float w1 = m1 * dinv[s1];
        float4 v0 = *(const float4*)&x[(size_t)s0 * 64 + 4 * c];
        float4 v1 = *(const float4*)&x[(size_t)s1 * 64 + 4 * c];
        aA.x += w0 * v0.x + w1 * v1.x; aA.y += w0 * v0.y + w1 * v1.y;
        aA.z += w0 * v0.z + w1 * v1.z; aA.w += w0 * v0.w + w1 * v1.w;
        aB.x += m0 * v0.x + m1 * v1.x; aB.y += m0 * v0.y + m1 * v1.y;
        aB.z += m0 * v0.z + m1 * v1.z; aB.w += m0 * v0.w + m1 * v1.w;
    }
    xor_reduce8(aA, aB);

    if (grp == 0) {
        float4 xs = *(const float4*)&x[(size_t)node * 64 + 4 * c];
        float d2 = di * di;
        float4 g;
        g.x = di * aA.x + d2 * xs.x; g.y = di * aA.y + d2 * xs.y;
        g.z = di * aA.z + d2 * xs.z; g.w = di * aA.w + d2 * xs.w;
        *(float4*)&buf1[(size_t)node * 128 + 4 * c] = g;
    } else if (grp == 1) {
        float rn = 1.0f / fmaxf((float)cn, 1.0f);
        float4 s;
        s.x = aB.x * rn; s.y = aB.y * rn; s.z = aB.z * rn; s.w = aB.w * rn;
        *(float4*)&buf1[(size_t)node * 128 + 64 + 4 * c] = s;
    }
}

// Layer-1 GEMMs: block=1024 (16 waves), 2 nodes/wave. Weights transposed in
// LDS stride-68 (lane column contiguous -> ds_read_b128); inputs read as
// wave-uniform global float4 (scalar-cache broadcast). In-place: reads
// buf1[node] (gin|sin), writes back (g|s1). Row touched by one wave only.
__launch_bounds__(1024)
__global__ void k_gemm1(const float* __restrict__ x, float* __restrict__ buf1,
                        const float* __restrict__ W1, const float* __restrict__ b1,
                        const float* __restrict__ Wl1, const float* __restrict__ bl1,
                        const float* __restrict__ Wr1, int N) {
    __shared__ float sW1[64 * 68], sWl[64 * 68], sWr[64 * 68];
    int t = threadIdx.x;
    for (int i = t; i < 4096; i += 1024) {
        int k = i >> 6, o = i & 63;
        sW1[o * 68 + k] = W1[i];
        sWl[o * 68 + k] = Wl1[i];
        sWr[o * 68 + k] = Wr1[i];
    }
    __syncthreads();

    int lane = t & 63;
    int wave = t >> 6;
    int n0 = (blockIdx.x * 16 + wave) * 2;
    if (n0 >= N) return;
    int n1 = (n0 + 1 < N) ? n0 + 1 : n0;
    n0 = __builtin_amdgcn_readfirstlane(n0);
    n1 = __builtin_amdgcn_readfirstlane(n1);

    const float* r0 = buf1 + (size_t)n0 * 128;
    const float* r1 = buf1 + (size_t)n1 * 128;
    const float* x0 = x + (size_t)n0 * 64;
    const float* x1 = x + (size_t)n1 * 64;

    float accG0 = 0.f, accS0 = 0.f, accG1 = 0.f, accS1 = 0.f;
    #pragma unroll
    for (int kq = 0; kq < 16; ++kq) {
        float4 w1 = *(const float4*)&sW1[lane * 68 + 4 * kq];
        float4 wl = *(const float4*)&sWl[lane * 68 + 4 * kq];
        float4 wr = *(const float4*)&sWr[lane * 68 + 4 * kq];
        float4 a0 = *(const float4*)&r0[4 * kq];        // gin n0
        float4 b0 = *(const float4*)&r0[64 + 4 * kq];   // sin n0
        float4 c0 = *(const float4*)&x0[4 * kq];        // x   n0
        float4 a1 = *(const float4*)&r1[4 * kq];
        float4 b1v = *(const float4*)&r1[64 + 4 * kq];
        float4 c1 = *(const float4*)&x1[4 * kq];
        accG0 += a0.x * w1.x + a0.y * w1.y + a0.z * w1.z + a0.w * w1.w;
        accS0 += b0.x * wl.x + b0.y * wl.y + b0.z * wl.z + b0.w * wl.w
               + c0.x * wr.x + c0.y * wr.y + c0.z * wr.z + c0.w * wr.w;
        accG1 += a1.x * w1.x + a1.y * w1.y + a1.z * w1.z + a1.w * w1.w;
        accS1 += b1v.x * wl.x + b1v.y * wl.y + b1v.z * wl.z + b1v.w * wl.w
               + c1.x * wr.x + c1.y * wr.y + c1.z * wr.z + c1.w * wr.w;
    }
    float bg = b1[lane], bs = bl1[lane];
    buf1[(size_t)n0 * 128 + lane]      = fmaxf(accG0 + bg, 0.f);
    buf1[(size_t)n0 * 128 + 64 + lane] = fmaxf(accS0 + bs, 0.f);
    if (n1 != n0) {
        buf1[(size_t)n1 * 128 + lane]      = fmaxf(accG1 + bg, 0.f);
        buf1[(size_t)n1 * 128 + 64 + lane] = fmaxf(accS1 + bs, 0.f);
    }
}

// Layer 2 fused: gather(g,s1) -> GEMMs -> LN -> concat-proj -> out.
// One wave per node. Gather uses float4-lane groups; aggregates staged to a
// per-wave LDS slot with ONE ds_write_b128 (lane groups 0/1/2 write
// g2in/s2in/sv quads), then read back as wave-uniform b128 broadcasts.
__launch_bounds__(1024)
__global__ void k_layer2_fused(const float* __restrict__ gs, const int* __restrict__ csr,
                               const int* __restrict__ offs, const int* __restrict__ cnt,
                               const float* __restrict__ dinv,
                               const float* __restrict__ W2, const float* __restrict__ b2,
                               const float* __restrict__ Wl2, const float* __restrict__ bl2,
                               const float* __restrict__ Wr2,
                               const float* __restrict__ lngG, const float* __restrict__ lnbG,
                               const float* __restrict__ lngS, const float* __restrict__ lnbS,
                               const float* __restrict__ Pw, const float* __restrict__ Pb,
                               float* __restrict__ out, int N) {
    __shared__ float sW2[64 * 68], sWl[64 * 68], sWr[64 * 68];
    __shared__ float sPt[64 * 132];
    __shared__ float sS[16 * 192];
    int t = threadIdx.x;
    for (int i = t; i < 4096; i += 1024) {
        int k = i >> 6, o = i & 63;
        sW2[o * 68 + k] = W2[i];
        sWl[o * 68 + k] = Wl2[i];
        sWr[o * 68 + k] = Wr2[i];
    }
    for (int i = t; i < 8192; i += 1024) {
        int k = i >> 6, o = i & 63;
        sPt[o * 132 + k] = Pw[i];
    }
    __syncthreads();

    int lane = t & 63;
    int wave = t >> 6;
    int node = blockIdx.x * 16 + wave;
    if (node >= N) return;
    int c = lane & 15, grp = lane >> 4;
    int wbase = wave * 192;

    int st = offs[node];
    int cn = cnt[node];
    float di = dinv[node];

    // gather phase: accC = sum dinv[s]*g[s] quad, accD = sum s1[s] quad
    float4 aC = {0.f, 0.f, 0.f, 0.f}, aD = {0.f, 0.f, 0.f, 0.f};
    for (int e = 0; e < cn; e += 8) {
        int i0 = e + grp, i1 = e + 4 + grp;
        float m0 = (i0 < cn) ? 1.f : 0.f;
        float m1 = (i1 < cn) ? 1.f : 0.f;
        int s0 = csr[st + (i0 < cn ? i0 : cn - 1)];
        int s1 = csr[st + (i1 < cn ? i1 : cn - 1)];
        float w0 = m0 * dinv[s0];
        float w1 = m1 * dinv[s1];
        const float* p0 = gs + (size_t)s0 * 128 + 4 * c;
        const float* p1 = gs + (size_t)s1 * 128 + 4 * c;
        float4 g0 = *(const float4*)p0;
        float4 g1 = *(const float4*)p1;
        float4 t0 = *(const float4*)(p0 + 64);
        float4 t1 = *(const float4*)(p1 + 64);
        aC.x += w0 * g0.x + w1 * g1.x; aC.y += w0 * g0.y + w1 * g1.y;
        aC.z += w0 * g0.z + w1 * g1.z; aC.w += w0 * g0.w + w1 * g1.w;
        aD.x += m0 * t0.x + m1 * t1.x; aD.y += m0 * t0.y + m1 * t1.y;
        aD.z += m0 * t0.z + m1 * t1.z; aD.w += m0 * t0.w + m1 * t1.w;
    }
    xor_reduce8(aC, aD);

    // stage g2in | s2in | sv quads with one predicated b128 write
    {
        float4 selfq = *(const float4*)&gs[(size_t)node * 128 + (grp == 2 ? 64 : 0) + 4 * c];
        float4 val;
        if (grp == 0) {
            float d2 = di * di;
            val.x = di * aC.x + d2 * selfq.x; val.y = di * aC.y + d2 * selfq.y;
            val.z = di * aC.z + d2 * selfq.z; val.w = di * aC.w + d2 * selfq.w;
        } else if (grp == 1) {
            float rn = 1.0f / fmaxf((float)cn, 1.0f);
            val.x = aD.x * rn; val.y = aD.y * rn; val.z = aD.z * rn; val.w = aD.w * rn;
        } else {
            val = selfq;  // sv quad (grp==2); grp==3 masked off
        }
        if (grp < 3) *(float4*)&sS[wbase + grp * 64 + 4 * c] = val;
    }

    // z-GEMMs
    float accG = 0.f, accS = 0.f;
    #pragma unroll
    for (int kq = 0; kq < 16; ++kq) {
        float4 w2 = *(const float4*)&sW2[lane * 68 + 4 * kq];
        float4 wl = *(const float4*)&sWl[lane * 68 + 4 * kq];
        float4 wr = *(const float4*)&sWr[lane * 68 + 4 * kq];
        float4 ia = *(const float4*)&sS[wbase + 4 * kq];
        float4 ib = *(const float4*)&sS[wbase + 64 + 4 * kq];
        float4 ic = *(const float4*)&sS[wbase + 128 + 4 * kq];
        accG += ia.x * w2.x + ia.y * w2.y + ia.z * w2.z + ia.w * w2.w;
        accS += ib.x * wl.x + ib.y * wl.y + ib.z * wl.z + ib.w * wl.w
              + ic.x * wr.x + ic.y * wr.y + ic.z * wr.z + ic.w * wr.w;
    }
    accG += b2[lane];
    accS += bl2[lane];

    // LayerNorm both branches (64-lane butterfly)
    float sG = accG, qG = accG * accG, sSs = accS, qS = accS * accS;
    #pragma unroll
    for (int m = 1; m < 64; m <<= 1) {
        sG += __shfl_xor(sG, m, 64);
        qG += __shfl_xor(qG, m, 64);
        sSs += __shfl_xor(sSs, m, 64);
        qS += __shfl_xor(qS, m, 64);
    }
    float muG = sG * (1.0f / 64.0f);
    float varG = fmaxf(qG * (1.0f / 64.0f) - muG * muG, 0.0f);
    float muS = sSs * (1.0f / 64.0f);
    float varS = fmaxf(qS * (1.0f / 64.0f) - muS * muS, 0.0f);
    float gln = (accG - muG) * rsqrtf(varG + 1e-5f) * lngG[lane] + lnbG[lane];
    float sln = (accS - muS) * rsqrtf(varS + 1e-5f) * lngS[lane] + lnbS[lane];

    // stage LN outputs (overwrite wave slot; wave-local ordering is safe)
    sS[wbase + lane] = gln;
    sS[wbase + 64 + lane] = sln;

    // proj: out[o] = sum_k cat[k] * P[k][o] + Pb[o]
    float accO = Pb[lane];
    #pragma unroll
    for (int kq = 0; kq < 16; ++kq) {
        float4 p = *(const float4*)&sPt[lane * 132 + 4 * kq];
        float4 u = *(const float4*)&sS[wbase + 4 * kq];
        accO += u.x * p.x + u.y * p.y + u.z * p.z + u.w * p.w;
    }
    #pragma unroll
    for (int kq = 0; kq < 16; ++kq) {
        float4 p = *(const float4*)&sPt[lane * 132 + 64 + 4 * kq];
        float4 u = *(const float4*)&sS[wbase + 64 + 4 * kq];
        accO += u.x * p.x + u.y * p.y + u.z * p.z + u.w * p.w;
    }
    out[(size_t)node * 64 + lane] = accO;
}

extern "C" void kernel_launch(void* const* d_in, const int* in_sizes, int n_in,
                              void* d_out, int out_size, void* d_ws, size_t ws_size,
                              hipStream_t stream) {
    const float* x        = (const float*)d_in[0];
    const int*   ei       = (const int*)d_in[1];
    const float* gcn_w1   = (const float*)d_in[2];
    const float* gcn_b1   = (const float*)d_in[3];
    const float* gcn_w2   = (const float*)d_in[4];
    const float* gcn_b2   = (const float*)d_in[5];
    const float* sage_wl1 = (const float*)d_in[6];
    const float* sage_bl1 = (const float*)d_in[7];
    const float* sage_wr1 = (const float*)d_in[8];
    const float* sage_wl2 = (const float*)d_in[9];
    const float* sage_bl2 = (const float*)d_in[10];
    const float* sage_wr2 = (const float*)d_in[11];
    const float* gcn_ln_g = (const float*)d_in[12];
    const float* gcn_ln_b = (const float*)d_in[13];
    const float* sage_ln_g = (const float*)d_in[14];
    const float* sage_ln_b = (const float*)d_in[15];
    const float* proj_w   = (const float*)d_in[16];
    const float* proj_b   = (const float*)d_in[17];
    float* out = (float*)d_out;

    const int N = in_sizes[0] / 64;
    const int E = in_sizes[1] / 2;
    const int B = (N + SCAN_CHUNK - 1) / SCAN_CHUNK;

    char* w = (char*)d_ws;
    size_t off = 0;
    auto alloc = [&](size_t bytes) -> void* {
        void* p = w + off;
        off = (off + bytes + 255) & ~(size_t)255;
        return p;
    };
    int*   cnt       = (int*)alloc((size_t)N * 4);
    int*   offs      = (int*)alloc((size_t)N * 4);
    int*   cursor    = (int*)alloc((size_t)N * 4);
    float* dinv      = (float*)alloc((size_t)N * 4);
    int*   blockSums = (int*)alloc((size_t)(B + 1) * 4);
    int*   csr       = (int*)alloc((size_t)E * 4);
    float* buf1      = (float*)alloc((size_t)N * 128 * 4);  // agg1 -> (in-place) gs
    (void)ws_size; (void)n_in; (void)out_size;

    hipMemsetAsync(cnt, 0, (size_t)N * 4, stream);
    hipMemsetAsync(cursor, 0, (size_t)N * 4, stream);

    int e4Blocks = ((E + 3) / 4 + 255) / 256;
    k_count<<<e4Blocks, 256, 0, stream>>>(ei, E, cnt);
    k_scan_reduce<<<B, 256, 0, stream>>>(cnt, N, blockSums);
    k_scan_spine<<<1, 64, 0, stream>>>(blockSums, B);
    k_scan_write<<<B, 256, 0, stream>>>(cnt, N, blockSums, offs, dinv);
    k_fill<<<e4Blocks, 256, 0, stream>>>(ei, E, offs, cursor, csr);

    k_gather1<<<(N + 3) / 4, 256, 0, stream>>>(x, csr, offs, cnt, dinv, buf1, N);
    k_gemm1<<<(N + 31) / 32, 1024, 0, stream>>>(x, buf1, gcn_w1, gcn_b1,
                                                sage_wl1, sage_bl1, sage_wr1, N);
    k_layer2_fused<<<(N + 15) / 16, 1024, 0, stream>>>(buf1, csr, offs, cnt, dinv,
                                                       gcn_w2, gcn_b2, sage_wl2, sage_bl2,
                                                       sage_wr2, gcn_ln_g, gcn_ln_b,
                                                       sage_ln_g, sage_ln_b, proj_w, proj_b,
                                                       out, N);
}

// Round 3
// 679.463 us; speedup vs baseline: 1.7121x; 1.3923x over previous
//
#include <hip/hip_runtime.h>

// N=100000 nodes, E=1250000 edges, all dims 64. fp32 end-to-end.
// R3: k_gemm1's wave-uniform GLOBAL broadcast datapath was pathological
// (400us, 1.6GB HBM traffic for a 2.5GFLOP GEMM). Replaced gather1+gemm1
// with k_layer1_fused using the measured-good layer2_fused structure:
// broadcasts from per-wave LDS slot, per-lane-distinct ds_read_b128 weights.

#define SCAN_CHUNK 2048

__global__ void k_count(const int* __restrict__ ei, int E, int* __restrict__ cnt) {
    int i = blockIdx.x * blockDim.x + threadIdx.x;
    int e = i * 4;
    if (e + 4 <= E) {
        int4 d = *(const int4*)&ei[E + e];
        atomicAdd(&cnt[d.x], 1); atomicAdd(&cnt[d.y], 1);
        atomicAdd(&cnt[d.z], 1); atomicAdd(&cnt[d.w], 1);
    } else {
        for (int j = e; j < E; ++j) atomicAdd(&cnt[ei[E + j]], 1);
    }
}

__global__ void k_scan_reduce(const int* __restrict__ cnt, int N, int* __restrict__ blockSums) {
    __shared__ int lds[256];
    int base = blockIdx.x * SCAN_CHUNK;
    int t = threadIdx.x;
    int s = 0;
    for (int j = 0; j < 8; ++j) {
        int idx = base + t * 8 + j;
        if (idx < N) s += cnt[idx];
    }
    lds[t] = s;
    __syncthreads();
    for (int d = 128; d > 0; d >>= 1) {
        if (t < d) lds[t] += lds[t + d];
        __syncthreads();
    }
    if (t == 0) blockSums[blockIdx.x] = lds[0];
}

__global__ void k_scan_spine(int* __restrict__ blockSums, int B) {
    if (threadIdx.x == 0 && blockIdx.x == 0) {
        int run = 0;
        for (int b = 0; b < B; ++b) { int v = blockSums[b]; blockSums[b] = run; run += v; }
    }
}

__global__ void k_scan_write(const int* __restrict__ cnt, int N,
                             const int* __restrict__ blockSums,
                             int* __restrict__ offs, float* __restrict__ dinv) {
    __shared__ int lds[256];
    int base = blockIdx.x * SCAN_CHUNK;
    int t = threadIdx.x;
    int v[8];
    int s = 0;
    for (int j = 0; j < 8; ++j) {
        int idx = base + t * 8 + j;
        v[j] = (idx < N) ? cnt[idx] : 0;
        s += v[j];
    }
    lds[t] = s;
    __syncthreads();
    for (int d = 1; d < 256; d <<= 1) {
        int x = (t >= d) ? lds[t - d] : 0;
        __syncthreads();
        lds[t] += x;
        __syncthreads();
    }
    int excl = (t == 0) ? 0 : lds[t - 1];
    int run = blockSums[blockIdx.x] + excl;
    for (int j = 0; j < 8; ++j) {
        int idx = base + t * 8 + j;
        if (idx < N) {
            offs[idx] = run;
            run += v[j];
            dinv[idx] = rsqrtf((float)v[j] + 1.0f);
        }
    }
}

__global__ void k_fill(const int* __restrict__ ei, int E, const int* __restrict__ offs,
                       int* __restrict__ cursor, int* __restrict__ csr) {
    int i = blockIdx.x * blockDim.x + threadIdx.x;
    int e = i * 4;
    if (e + 4 <= E) {
        int4 s = *(const int4*)&ei[e];
        int4 d = *(const int4*)&ei[E + e];
        csr[offs[d.x] + atomicAdd(&cursor[d.x], 1)] = s.x;
        csr[offs[d.y] + atomicAdd(&cursor[d.y], 1)] = s.y;
        csr[offs[d.z] + atomicAdd(&cursor[d.z], 1)] = s.z;
        csr[offs[d.w] + atomicAdd(&cursor[d.w], 1)] = s.w;
    } else {
        for (int j = e; j < E; ++j) {
            int s = ei[j], d = ei[E + j];
            csr[offs[d] + atomicAdd(&cursor[d], 1)] = s;
        }
    }
}

__device__ __forceinline__ void xor_reduce8(float4& a, float4& b) {
    a.x += __shfl_xor(a.x, 16, 64); a.y += __shfl_xor(a.y, 16, 64);
    a.z += __shfl_xor(a.z, 16, 64); a.w += __shfl_xor(a.w, 16, 64);
    b.x += __shfl_xor(b.x, 16, 64); b.y += __shfl_xor(b.y, 16, 64);
    b.z += __shfl_xor(b.z, 16, 64); b.w += __shfl_xor(b.w, 16, 64);
    a.x += __shfl_xor(a.x, 32, 64); a.y += __shfl_xor(a.y, 32, 64);
    a.z += __shfl_xor(a.z, 32, 64); a.w += __shfl_xor(a.w, 32, 64);
    b.x += __shfl_xor(b.x, 32, 64); b.y += __shfl_xor(b.y, 32, 64);
    b.z += __shfl_xor(b.z, 32, 64); b.w += __shfl_xor(b.w, 32, 64);
}

// Layer 1 fused: gather x (GCN-weighted + SAGE-sum) -> stage to wave LDS slot
// -> fused GEMMs (lane=output, transposed stride-68 weights, ds_read_b128)
// -> relu -> buf1[node] = (g | s1). One wave per node.
__launch_bounds__(1024)
__global__ void k_layer1_fused(const float* __restrict__ x, const int* __restrict__ csr,
                               const int* __restrict__ offs, const int* __restrict__ cnt,
                               const float* __restrict__ dinv,
                               const float* __restrict__ W1, const float* __restrict__ b1,
                               const float* __restrict__ Wl1, const float* __restrict__ bl1,
                               const float* __restrict__ Wr1,
                               float* __restrict__ buf1, int N) {
    __shared__ float sW1[64 * 68], sWl[64 * 68], sWr[64 * 68];
    __shared__ float sS[16 * 192];
    int t = threadIdx.x;
    for (int i = t; i < 4096; i += 1024) {
        int k = i >> 6, o = i & 63;
        sW1[o * 68 + k] = W1[i];
        sWl[o * 68 + k] = Wl1[i];
        sWr[o * 68 + k] = Wr1[i];
    }
    __syncthreads();

    int lane = t & 63;
    int wave = t >> 6;
    int node = blockIdx.x * 16 + wave;
    if (node >= N) return;
    int c = lane & 15, grp = lane >> 4;
    int wbase = wave * 192;

    int st = offs[node];
    int cn = cnt[node];
    float di = dinv[node];

    float4 aA = {0.f, 0.f, 0.f, 0.f}, aB = {0.f, 0.f, 0.f, 0.f};
    for (int e = 0; e < cn; e += 8) {
        int i0 = e + grp, i1 = e + 4 + grp;
        float m0 = (i0 < cn) ? 1.f : 0.f;
        float m1 = (i1 < cn) ? 1.f : 0.f;
        int s0 = csr[st + (i0 < cn ? i0 : cn - 1)];
        int s1 = csr[st + (i1 < cn ? i1 : cn - 1)];
        float w0 = m0 * dinv[s0];
        float w1 = m1 * dinv[s1];
        float4 v0 = *(const float4*)&x[(size_t)s0 * 64 + 4 * c];
        float4 v1 = *(const float4*)&x[(size_t)s1 * 64 + 4 * c];
        aA.x += w0 * v0.x + w1 * v1.x; aA.y += w0 * v0.y + w1 * v1.y;
        aA.z += w0 * v0.z + w1 * v1.z; aA.w += w0 * v0.w + w1 * v1.w;
        aB.x += m0 * v0.x + m1 * v1.x; aB.y += m0 * v0.y + m1 * v1.y;
        aB.z += m0 * v0.z + m1 * v1.z; aB.w += m0 * v0.w + m1 * v1.w;
    }
    xor_reduce8(aA, aB);

    // stage gin | sin | xv quads with one predicated b128 write
    {
        float4 selfq = *(const float4*)&x[(size_t)node * 64 + 4 * c];
        float4 val;
        if (grp == 0) {
            float d2 = di * di;
            val.x = di * aA.x + d2 * selfq.x; val.y = di * aA.y + d2 * selfq.y;
            val.z = di * aA.z + d2 * selfq.z; val.w = di * aA.w + d2 * selfq.w;
        } else if (grp == 1) {
            float rn = 1.0f / fmaxf((float)cn, 1.0f);
            val.x = aB.x * rn; val.y = aB.y * rn; val.z = aB.z * rn; val.w = aB.w * rn;
        } else {
            val = selfq;  // xv quad (grp==2); grp==3 masked off
        }
        if (grp < 3) *(float4*)&sS[wbase + grp * 64 + 4 * c] = val;
    }

    float accG = b1[lane], accS = bl1[lane];
    #pragma unroll
    for (int kq = 0; kq < 16; ++kq) {
        float4 w1 = *(const float4*)&sW1[lane * 68 + 4 * kq];
        float4 wl = *(const float4*)&sWl[lane * 68 + 4 * kq];
        float4 wr = *(const float4*)&sWr[lane * 68 + 4 * kq];
        float4 ia = *(const float4*)&sS[wbase + 4 * kq];         // gin
        float4 ib = *(const float4*)&sS[wbase + 64 + 4 * kq];    // sin
        float4 ic = *(const float4*)&sS[wbase + 128 + 4 * kq];   // xv
        accG += ia.x * w1.x + ia.y * w1.y + ia.z * w1.z + ia.w * w1.w;
        accS += ib.x * wl.x + ib.y * wl.y + ib.z * wl.z + ib.w * wl.w
              + ic.x * wr.x + ic.y * wr.y + ic.z * wr.z + ic.w * wr.w;
    }
    buf1[(size_t)node * 128 + lane]      = fmaxf(accG, 0.f);
    buf1[(size_t)node * 128 + 64 + lane] = fmaxf(accS, 0.f);
}

// Layer 2 fused: gather(g,s1) -> GEMMs -> LN -> concat-proj -> out.
__launch_bounds__(1024)
__global__ void k_layer2_fused(const float* __restrict__ gs, const int* __restrict__ csr,
                               const int* __restrict__ offs, const int* __restrict__ cnt,
                               const float* __restrict__ dinv,
                               const float* __restrict__ W2, const float* __restrict__ b2,
                               const float* __restrict__ Wl2, const float* __restrict__ bl2,
                               const float* __restrict__ Wr2,
                               const float* __restrict__ lngG, const float* __restrict__ lnbG,
                               const float* __restrict__ lngS, const float* __restrict__ lnbS,
                               const float* __restrict__ Pw, const float* __restrict__ Pb,
                               float* __restrict__ out, int N) {
    __shared__ float sW2[64 * 68], sWl[64 * 68], sWr[64 * 68];
    __shared__ float sPt[64 * 132];
    __shared__ float sS[16 * 192];
    int t = threadIdx.x;
    for (int i = t; i < 4096; i += 1024) {
        int k = i >> 6, o = i & 63;
        sW2[o * 68 + k] = W2[i];
        sWl[o * 68 + k] = Wl2[i];
        sWr[o * 68 + k] = Wr2[i];
    }
    for (int i = t; i < 8192; i += 1024) {
        int k = i >> 6, o = i & 63;
        sPt[o * 132 + k] = Pw[i];
    }
    __syncthreads();

    int lane = t & 63;
    int wave = t >> 6;
    int node = blockIdx.x * 16 + wave;
    if (node >= N) return;
    int c = lane & 15, grp = lane >> 4;
    int wbase = wave * 192;

    int st = offs[node];
    int cn = cnt[node];
    float di = dinv[node];

    float4 aC = {0.f, 0.f, 0.f, 0.f}, aD = {0.f, 0.f, 0.f, 0.f};
    for (int e = 0; e < cn; e += 8) {
        int i0 = e + grp, i1 = e + 4 + grp;
        float m0 = (i0 < cn) ? 1.f : 0.f;
        float m1 = (i1 < cn) ? 1.f : 0.f;
        int s0 = csr[st + (i0 < cn ? i0 : cn - 1)];
        int s1 = csr[st + (i1 < cn ? i1 : cn - 1)];
        float w0 = m0 * dinv[s0];
        float w1 = m1 * dinv[s1];
        const float* p0 = gs + (size_t)s0 * 128 + 4 * c;
        const float* p1 = gs + (size_t)s1 * 128 + 4 * c;
        float4 g0 = *(const float4*)p0;
        float4 g1 = *(const float4*)p1;
        float4 t0 = *(const float4*)(p0 + 64);
        float4 t1 = *(const float4*)(p1 + 64);
        aC.x += w0 * g0.x + w1 * g1.x; aC.y += w0 * g0.y + w1 * g1.y;
        aC.z += w0 * g0.z + w1 * g1.z; aC.w += w0 * g0.w + w1 * g1.w;
        aD.x += m0 * t0.x + m1 * t1.x; aD.y += m0 * t0.y + m1 * t1.y;
        aD.z += m0 * t0.z + m1 * t1.z; aD.w += m0 * t0.w + m1 * t1.w;
    }
    xor_reduce8(aC, aD);

    {
        float4 selfq = *(const float4*)&gs[(size_t)node * 128 + (grp == 2 ? 64 : 0) + 4 * c];
        float4 val;
        if (grp == 0) {
            float d2 = di * di;
            val.x = di * aC.x + d2 * selfq.x; val.y = di * aC.y + d2 * selfq.y;
            val.z = di * aC.z + d2 * selfq.z; val.w = di * aC.w + d2 * selfq.w;
        } else if (grp == 1) {
            float rn = 1.0f / fmaxf((float)cn, 1.0f);
            val.x = aD.x * rn; val.y = aD.y * rn; val.z = aD.z * rn; val.w = aD.w * rn;
        } else {
            val = selfq;  // sv quad (grp==2); grp==3 masked off
        }
        if (grp < 3) *(float4*)&sS[wbase + grp * 64 + 4 * c] = val;
    }

    float accG = 0.f, accS = 0.f;
    #pragma unroll
    for (int kq = 0; kq < 16; ++kq) {
        float4 w2 = *(const float4*)&sW2[lane * 68 + 4 * kq];
        float4 wl = *(const float4*)&sWl[lane * 68 + 4 * kq];
        float4 wr = *(const float4*)&sWr[lane * 68 + 4 * kq];
        float4 ia = *(const float4*)&sS[wbase + 4 * kq];
        float4 ib = *(const float4*)&sS[wbase + 64 + 4 * kq];
        float4 ic = *(const float4*)&sS[wbase + 128 + 4 * kq];
        accG += ia.x * w2.x + ia.y * w2.y + ia.z * w2.z + ia.w * w2.w;
        accS += ib.x * wl.x + ib.y * wl.y + ib.z * wl.z + ib.w * wl.w
              + ic.x * wr.x + ic.y * wr.y + ic.z * wr.z + ic.w * wr.w;
    }
    accG += b2[lane];
    accS += bl2[lane];

    float sG = accG, qG = accG * accG, sSs = accS, qS = accS * accS;
    #pragma unroll
    for (int m = 1; m < 64; m <<= 1) {
        sG += __shfl_xor(sG, m, 64);
        qG += __shfl_xor(qG, m, 64);
        sSs += __shfl_xor(sSs, m, 64);
        qS += __shfl_xor(qS, m, 64);
    }
    float muG = sG * (1.0f / 64.0f);
    float varG = fmaxf(qG * (1.0f / 64.0f) - muG * muG, 0.0f);
    float muS = sSs * (1.0f / 64.0f);
    float varS = fmaxf(qS * (1.0f / 64.0f) - muS * muS, 0.0f);
    float gln = (accG - muG) * rsqrtf(varG + 1e-5f) * lngG[lane] + lnbG[lane];
    float sln = (accS - muS) * rsqrtf(varS + 1e-5f) * lngS[lane] + lnbS[lane];

    sS[wbase + lane] = gln;
    sS[wbase + 64 + lane] = sln;

    float accO = Pb[lane];
    #pragma unroll
    for (int kq = 0; kq < 16; ++kq) {
        float4 p = *(const float4*)&sPt[lane * 132 + 4 * kq];
        float4 u = *(const float4*)&sS[wbase + 4 * kq];
        accO += u.x * p.x + u.y * p.y + u.z * p.z + u.w * p.w;
    }
    #pragma unroll
    for (int kq = 0; kq < 16; ++kq) {
        float4 p = *(const float4*)&sPt[lane * 132 + 64 + 4 * kq];
        float4 u = *(const float4*)&sS[wbase + 64 + 4 * kq];
        accO += u.x * p.x + u.y * p.y + u.z * p.z + u.w * p.w;
    }
    out[(size_t)node * 64 + lane] = accO;
}

extern "C" void kernel_launch(void* const* d_in, const int* in_sizes, int n_in,
                              void* d_out, int out_size, void* d_ws, size_t ws_size,
                              hipStream_t stream) {
    const float* x        = (const float*)d_in[0];
    const int*   ei       = (const int*)d_in[1];
    const float* gcn_w1   = (const float*)d_in[2];
    const float* gcn_b1   = (const float*)d_in[3];
    const float* gcn_w2   = (const float*)d_in[4];
    const float* gcn_b2   = (const float*)d_in[5];
    const float* sage_wl1 = (const float*)d_in[6];
    const float* sage_bl1 = (const float*)d_in[7];
    const float* sage_wr1 = (const float*)d_in[8];
    const float* sage_wl2 = (const float*)d_in[9];
    const float* sage_bl2 = (const float*)d_in[10];
    const float* sage_wr2 = (const float*)d_in[11];
    const float* gcn_ln_g = (const float*)d_in[12];
    const float* gcn_ln_b = (const float*)d_in[13];
    const float* sage_ln_g = (const float*)d_in[14];
    const float* sage_ln_b = (const float*)d_in[15];
    const float* proj_w   = (const float*)d_in[16];
    const float* proj_b   = (const float*)d_in[17];
    float* out = (float*)d_out;

    const int N = in_sizes[0] / 64;
    const int E = in_sizes[1] / 2;
    const int B = (N + SCAN_CHUNK - 1) / SCAN_CHUNK;

    char* w = (char*)d_ws;
    size_t off = 0;
    auto alloc = [&](size_t bytes) -> void* {
        void* p = w + off;
        off = (off + bytes + 255) & ~(size_t)255;
        return p;
    };
    int*   cnt       = (int*)alloc((size_t)N * 4);
    int*   offs      = (int*)alloc((size_t)N * 4);
    int*   cursor    = (int*)alloc((size_t)N * 4);
    float* dinv      = (float*)alloc((size_t)N * 4);
    int*   blockSums = (int*)alloc((size_t)(B + 1) * 4);
    int*   csr       = (int*)alloc((size_t)E * 4);
    float* buf1      = (float*)alloc((size_t)N * 128 * 4);  // (g | s1)
    (void)ws_size; (void)n_in; (void)out_size;

    hipMemsetAsync(cnt, 0, (size_t)N * 4, stream);
    hipMemsetAsync(cursor, 0, (size_t)N * 4, stream);

    int e4Blocks = ((E + 3) / 4 + 255) / 256;
    k_count<<<e4Blocks, 256, 0, stream>>>(ei, E, cnt);
    k_scan_reduce<<<B, 256, 0, stream>>>(cnt, N, blockSums);
    k_scan_spine<<<1, 64, 0, stream>>>(blockSums, B);
    k_scan_write<<<B, 256, 0, stream>>>(cnt, N, blockSums, offs, dinv);
    k_fill<<<e4Blocks, 256, 0, stream>>>(ei, E, offs, cursor, csr);

    k_layer1_fused<<<(N + 15) / 16, 1024, 0, stream>>>(x, csr, offs, cnt, dinv,
                                                       gcn_w1, gcn_b1, sage_wl1, sage_bl1,
                                                       sage_wr1, buf1, N);
    k_layer2_fused<<<(N + 15) / 16, 1024, 0, stream>>>(buf1, csr, offs, cnt, dinv,
                                                       gcn_w2, gcn_b2, sage_wl2, sage_bl2,
                                                       sage_wr2, gcn_ln_g, gcn_ln_b,
                                                       sage_ln_g, sage_ln_b, proj_w, proj_b,
                                                       out, N);
}